// Round 4
// baseline (147.276 us; speedup 1.0000x reference)
//
#include <hip/hip_runtime.h>
#include <hip/hip_bf16.h>
#include <math.h>

#define NQ 900
#define NT 100
#define BS 16
#define NH 7
#define NC 16
#define SLOTS 15     // 64 lanes * 15 slots = 960 >= 900 columns
#define MAXARR 512   // cap on total ARR row-scans (safety: bail -> tree stage handles)
#define MAXTREE 8192 // cap on tree inner iterations per phase (safety: no hang)

// ---------- Stage 1: fused cost kernel, one block per (b,t) ----------
__global__ __launch_bounds__(256) void cost_kernel(const float*  __restrict__ logits,   // (7,16,900,16)
                                                   const float4* __restrict__ pboxes4,  // (16,900)
                                                   const float4* __restrict__ tboxes4,  // (16,100)
                                                   const int*    __restrict__ tlabels,  // (7,16,100)
                                                   float* __restrict__ costT) {         // (16,100,900)
    const int bt = blockIdx.x;
    const int b = bt / NT, t = bt % NT;

    int lab[NH];
    #pragma unroll
    for (int h = 0; h < NH; ++h) lab[h] = tlabels[(h * BS + b) * NT + t];   // uniform -> scalar loads

    float4 tb = tboxes4[b * NT + t];
    float tx = tb.x, ty = tb.y, tw = tb.z, th = tb.w;
    float bx0 = tx - 0.5f * tw, by0 = ty - 0.5f * th;
    float bx1 = tx + 0.5f * tw, by1 = ty + 0.5f * th;
    float areaB = (bx1 - bx0) * (by1 - by0);

    for (int q = threadIdx.x; q < NQ; q += 256) {
        float4 pb = pboxes4[b * NQ + q];
        float px = pb.x, py = pb.y, pw = pb.z, ph = pb.w;

        float cost_bbox = fabsf(px - tx) + fabsf(py - ty) + fabsf(pw - tw) + fabsf(ph - th);

        float ax0 = px - 0.5f * pw, ay0 = py - 0.5f * ph;
        float ax1 = px + 0.5f * pw, ay1 = py + 0.5f * ph;
        float areaA = (ax1 - ax0) * (ay1 - ay0);
        float ltx = fmaxf(ax0, bx0), lty = fmaxf(ay0, by0);
        float rbx = fminf(ax1, bx1), rby = fminf(ay1, by1);
        float iw = fmaxf(rbx - ltx, 0.f), ih = fmaxf(rby - lty, 0.f);
        float inter = iw * ih;
        float uni = areaA + areaB - inter;
        float iou = inter / uni;
        float ex0 = fminf(ax0, bx0), ey0 = fminf(ay0, by0);
        float ex1 = fmaxf(ax1, bx1), ey1 = fmaxf(ay1, by1);
        float ew = fmaxf(ex1 - ex0, 0.f), eh = fmaxf(ey1 - ey0, 0.f);
        float earea = ew * eh;
        float giou = iou - (earea - uni) / earea;

        float ssum = 0.f;
        #pragma unroll
        for (int h = 0; h < NH; ++h) {
            float x = logits[(size_t)((h * BS + b) * NQ + q) * NC + lab[h]];
            ssum += 1.0f / (1.0f + expf(-x));      // same formula/order as R0 -> identical costT
        }

        costT[(b * NT + t) * NQ + q] = 5.0f * cost_bbox - 2.0f * ssum - 2.0f * giou;
    }
}

// ---------- Stage 2: JV LSA = greedy init + augmenting-row-reduction + SAP tree ----------
// Invariants kept throughout: duals feasible (c-u-v >= 0), every assigned arc tight.
// Final assignment is THE optimal one (unique for continuous random costs) == reference's.
// pu[j] = { u[p[j]], (double)p[j] } : one ds_read_b128 replaces two dependent LDS reads.
__global__ __launch_bounds__(64) void lsa_kernel(const float* __restrict__ costT,
                                                 int* __restrict__ out) {
    const int b = blockIdx.x;
    const int lane = threadIdx.x;
    const float* cost = costT + b * NT * NQ;   // [t][q]

    __shared__ double2 pu[NQ + 1];   // .x = u[p[j]], .y = p[j] (0 = free)
    __shared__ double u_s[NT + 1];
    __shared__ int way_s[NQ + 1];
    __shared__ int x_s[NT + 1];      // row -> col (0 = free)
    __shared__ int jmin_s[NT];
    __shared__ int unass[NT];
    __shared__ int r2c[NT];
    __shared__ int nun_s;

    for (int j = lane; j <= NQ; j += 64) pu[j] = make_double2(0.0, 0.0);
    __syncthreads();

    // ---- row minima + argmin (per-lane row, float4 scan) ----
    for (int base = 0; base < NT; base += 64) {
        int r = base + lane;
        if (r < NT) {
            const float4* row4 = (const float4*)(cost + (size_t)r * NQ);
            float m0 = INFINITY, m1f = INFINITY, m2f = INFINITY, m3f = INFINITY;
            int i0 = 0, i1 = 0, i2 = 0, i3 = 0;
            #pragma unroll 5
            for (int q4 = 0; q4 < NQ / 4; ++q4) {
                float4 cv = row4[q4];
                if (cv.x < m0)  { m0 = cv.x;  i0 = 4 * q4; }
                if (cv.y < m1f) { m1f = cv.y; i1 = 4 * q4 + 1; }
                if (cv.z < m2f) { m2f = cv.z; i2 = 4 * q4 + 2; }
                if (cv.w < m3f) { m3f = cv.w; i3 = 4 * q4 + 3; }
            }
            float mv = m0; int mj = i0;
            if (m1f < mv || (m1f == mv && i1 < mj)) { mv = m1f; mj = i1; }
            if (m2f < mv || (m2f == mv && i2 < mj)) { mv = m2f; mj = i2; }
            if (m3f < mv || (m3f == mv && i3 < mj)) { mv = m3f; mj = i3; }
            u_s[r + 1] = (double)mv;
            jmin_s[r] = mj;
        }
    }
    __syncthreads();

    // ---- greedy assignment (lane 0) ----
    if (lane == 0) {
        int nun = 0;
        for (int i = 1; i <= NT; ++i) {
            int j = jmin_s[i - 1] + 1;
            if ((int)pu[j].y == 0) { pu[j] = make_double2(u_s[i], (double)i); x_s[i] = j; }
            else                   { x_s[i] = 0; unass[nun++] = i; }
        }
        nun_s = nun;
    }
    __syncthreads();
    const int nun = nun_s;

    // lane-owned columns: slot k -> j = 1 + lane + 64*k
    double v[SLOTS], minv[SLOTS], ureg[SLOTS];
    int pof[SLOTS];
    #pragma unroll
    for (int k = 0; k < SLOTS; ++k) { v[k] = 0.0; ureg[k] = 0.0; pof[k] = 0; }
    const unsigned invalid = (lane < 4) ? 0u : (1u << 14);   // slot 14: j=897..960
    double u_c0 = 0.0;

    // ---- augmenting row reduction (wave-uniform; single wave so no barriers) ----
    {
        int steps = 0;
        for (int idx = 0; idx < nun; ++idx) {
            int i = unass[idx];
            while (i != 0 && steps < MAXARR) {
                ++steps;
                const float* crow = cost + (size_t)(i - 1) * NQ;
                float c[SLOTS];
                #pragma unroll
                for (int k = 0; k < SLOTS - 1; ++k) c[k] = crow[lane + 64 * k];
                c[SLOTS - 1] = (lane < 4) ? crow[lane + 64 * (SLOTS - 1)] : 0.0f;

                double m1 = INFINITY, m2 = INFINITY;
                int j1 = 2048;
                #pragma unroll
                for (int k = 0; k < SLOTS; ++k) {
                    if (!((invalid >> k) & 1u)) {
                        int j = 1 + lane + 64 * k;
                        double d = (double)c[k] - v[k];
                        if (d < m1 || (d == m1 && j < j1)) { m2 = m1; m1 = d; j1 = j; }
                        else if (d < m2) m2 = d;
                    }
                }
                #pragma unroll
                for (int off = 1; off < 64; off <<= 1) {
                    double om1 = __shfl_xor(m1, off);
                    double om2 = __shfl_xor(m2, off);
                    int oj1 = __shfl_xor(j1, off);
                    if (om1 < m1 || (om1 == m1 && oj1 < j1)) { m2 = fmin(m1, om2); m1 = om1; j1 = oj1; }
                    else { m2 = fmin(m2, om1); }
                }

                double2 t = pu[j1];          // broadcast read
                int k1 = (int)t.y;
                if (m1 == m2 && k1 != 0) break;   // degenerate tie: leave row free for tree stage

                if (m1 < m2) {
                    if (lane == ((j1 - 1) & 63)) {
                        int slot = (j1 - 1) >> 6;
                        #pragma unroll
                        for (int k = 0; k < SLOTS; ++k) if (k == slot) v[k] -= (m2 - m1);
                    }
                }
                if (lane == 0) {
                    u_s[i] = m2;
                    pu[j1] = make_double2(m2, (double)i);
                    x_s[i] = j1;
                    if (k1) x_s[k1] = 0;
                }
                i = k1;                       // dethroned row continues the chain
            }
        }
    }
    __syncthreads();

    // ---- rebuild free list ----
    if (lane == 0) {
        int n2 = 0;
        for (int i = 1; i <= NT; ++i) if (x_s[i] == 0) unass[n2++] = i;
        nun_s = n2;
    }
    __syncthreads();
    const int nun2 = nun_s;

    // ---- shortest-augmenting-path tree stage (structure proven in R1-R3) ----
    for (int ii = 0; ii < nun2; ++ii) {
        const int i = unass[ii];
        #pragma unroll
        for (int k = 0; k < SLOTS; ++k) minv[k] = INFINITY;
        unsigned used = invalid;
        int j0 = 0;
        int i0 = i;
        double u_i0 = u_s[i];
        int guard = 0;

        while (guard++ < MAXTREE) {
            // stage A: mark j0 used (owner lane records row + running u)
            if (j0 != 0) {
                if (lane == ((j0 - 1) & 63)) {
                    int slot = (j0 - 1) >> 6;
                    used |= (1u << slot);
                    #pragma unroll
                    for (int k = 0; k < SLOTS; ++k)
                        if (slot == k) { pof[k] = i0; ureg[k] = u_i0; }
                }
            } else {
                if (lane == 0) u_c0 = u_i0;
            }

            // row fetch (L2-resident)
            const float* crow = cost + (size_t)(i0 - 1) * NQ;
            float c[SLOTS];
            #pragma unroll
            for (int k = 0; k < SLOTS - 1; ++k) c[k] = crow[lane + 64 * k];
            c[SLOTS - 1] = (lane < 4) ? crow[lane + 64 * (SLOTS - 1)] : 0.0f;

            // stage B: scan free columns, update minv/way, local argmin (ascending j)
            double bv = INFINITY;
            int bj = 2048;
            #pragma unroll
            for (int k = 0; k < SLOTS; ++k) {
                if (!((used >> k) & 1u)) {
                    int j = 1 + lane + 64 * k;
                    double cur = ((double)c[k] - u_i0) - v[k];
                    if (cur < minv[k]) { minv[k] = cur; way_s[j] = j0; }
                    if (minv[k] < bv) { bv = minv[k]; bj = j; }
                }
            }
            // butterfly argmin over 64 lanes, tie -> smaller j
            #pragma unroll
            for (int off = 1; off < 64; off <<= 1) {
                double ov = __shfl_xor(bv, off);
                int oj = __shfl_xor(bj, off);
                if (ov < bv || (ov == bv && oj < bj)) { bv = ov; bj = oj; }
            }
            const double delta = bv;

            // stage D: dual update (exact reference order, register-resident)
            #pragma unroll
            for (int k = 0; k < SLOTS; ++k) {
                if ((used >> k) & 1u) { ureg[k] += delta; v[k] -= delta; }
                else                  { minv[k] -= delta; }
            }
            if (lane == 0) u_c0 += delta;

            // advance: single b128 read gives p[bj] and u[p[bj]]
            double2 t = pu[bj];
            j0 = bj;
            i0 = (int)t.y;
            u_i0 = t.x;
            if (i0 == 0) break;
        }

        __syncthreads();
        // owner writebacks: u of rows sitting on used columns (p unchanged for them)
        #pragma unroll
        for (int k = 0; k < SLOTS; ++k) {
            if (((used >> k) & 1u) && !((invalid >> k) & 1u)) {
                int j = 1 + lane + 64 * k;
                u_s[pof[k]] = ureg[k];
                pu[j] = make_double2(ureg[k], (double)pof[k]);
            }
        }
        __syncthreads();
        if (lane == 0) {
            u_s[i] = u_c0;
            int j = j0;
            while (j) {
                int jw = way_s[j];
                double2 t2 = (jw == 0) ? make_double2(u_c0, (double)i) : pu[jw];
                pu[j] = t2;
                j = jw;
            }
        }
        __syncthreads();
    }

    // ---- row2col + stable-argsort ranks ----
    for (int j = 1 + lane; j <= NQ; j += 64) {
        int pi = (int)pu[j].y;
        if (pi > 0) r2c[pi - 1] = j - 1;
    }
    __syncthreads();
    for (int t = lane; t < NT; t += 64) {
        int ccol = r2c[t];
        int rank = 0;
        for (int tt = 0; tt < NT; ++tt) rank += (r2c[tt] < ccol) ? 1 : 0;
        out[b * 2 * NT + rank] = ccol;         // out[b,0,rank] = pred idx
        out[b * 2 * NT + NT + rank] = t;       // out[b,1,rank] = target idx
    }
}

extern "C" void kernel_launch(void* const* d_in, const int* in_sizes, int n_in,
                              void* d_out, int out_size, void* d_ws, size_t ws_size,
                              hipStream_t stream) {
    const float* logits  = (const float*)d_in[0];  // (7,16,900,16)
    const float* pboxes  = (const float*)d_in[1];  // (16,900,4)
    const float* tboxes  = (const float*)d_in[2];  // (16,100,4)
    const int*   tlabels = (const int*)d_in[3];    // (7,16,100)
    int* out = (int*)d_out;                        // (16,2,100) int32
    float* costT = (float*)d_ws;                   // 1,440,000 floats = 5.76 MB

    cost_kernel<<<BS * NT, 256, 0, stream>>>(logits, (const float4*)pboxes,
                                             (const float4*)tboxes, tlabels, costT);
    lsa_kernel<<<BS, 64, 0, stream>>>(costT, out);
}

// Round 5
// 133.849 us; speedup vs baseline: 1.1003x; 1.1003x over previous
//
#include <hip/hip_runtime.h>
#include <hip/hip_bf16.h>
#include <math.h>

#define NQ 900
#define NT 100
#define BS 16
#define NH 7
#define NC 16
#define SLOTS 15      // 64 lanes * 15 slots = 960 >= 900 columns
#define MAXROUNDS 32  // Jacobi-ARR rounds cap (leftovers -> exact tree stage)
#define MAXTREE 8192  // per-phase tree guard (no hang on bug)

// ---------- Stage 1a: sigmoid + transpose probs: [h,b,q,c] -> [h,b,c,q] ----------
__global__ __launch_bounds__(256) void sig_transpose_kernel(const float* __restrict__ logits,
                                                            float* __restrict__ probsT) {
    const int hb = blockIdx.x;                       // 0..NH*BS-1
    const float* src = logits + (size_t)hb * NQ * NC;
    float* dst = probsT + (size_t)hb * NC * NQ;
    __shared__ float tile[NC][NQ + 1];
    for (int e = threadIdx.x; e < NQ * NC; e += 256) {
        int q = e >> 4, c = e & 15;
        float x = src[e];
        tile[c][q] = 1.0f / (1.0f + expf(-x));       // same formula as R0 -> identical costT
    }
    __syncthreads();
    for (int c = 0; c < NC; ++c)
        for (int q = threadIdx.x; q < NQ; q += 256)
            dst[c * NQ + q] = tile[c][q];
}

// ---------- Stage 1b: cost matrix (transposed [b][t][q]); one block per (b,t) ----------
__global__ __launch_bounds__(256) void cost_kernel_bt(const float4* __restrict__ pboxes4,
                                                      const float4* __restrict__ tboxes4,
                                                      const int*    __restrict__ tlabels,
                                                      const float*  __restrict__ probsT,
                                                      float* __restrict__ costT) {
    const int bt = blockIdx.x;
    const int b = bt / NT, t = bt % NT;

    const float* prow[NH];
    #pragma unroll
    for (int h = 0; h < NH; ++h) {
        int lab = tlabels[(h * BS + b) * NT + t];          // uniform -> scalar load
        prow[h] = probsT + (size_t)((h * BS + b) * NC + lab) * NQ;
    }

    float4 tb = tboxes4[b * NT + t];
    float tx = tb.x, ty = tb.y, tw = tb.z, th = tb.w;
    float bx0 = tx - 0.5f * tw, by0 = ty - 0.5f * th;
    float bx1 = tx + 0.5f * tw, by1 = ty + 0.5f * th;
    float areaB = (bx1 - bx0) * (by1 - by0);

    for (int q = threadIdx.x; q < NQ; q += 256) {
        float4 pb = pboxes4[b * NQ + q];
        float px = pb.x, py = pb.y, pw = pb.z, ph = pb.w;

        float cost_bbox = fabsf(px - tx) + fabsf(py - ty) + fabsf(pw - tw) + fabsf(ph - th);

        float ax0 = px - 0.5f * pw, ay0 = py - 0.5f * ph;
        float ax1 = px + 0.5f * pw, ay1 = py + 0.5f * ph;
        float areaA = (ax1 - ax0) * (ay1 - ay0);
        float ltx = fmaxf(ax0, bx0), lty = fmaxf(ay0, by0);
        float rbx = fminf(ax1, bx1), rby = fminf(ay1, by1);
        float iw = fmaxf(rbx - ltx, 0.f), ih = fmaxf(rby - lty, 0.f);
        float inter = iw * ih;
        float uni = areaA + areaB - inter;
        float iou = inter / uni;
        float ex0 = fminf(ax0, bx0), ey0 = fminf(ay0, by0);
        float ex1 = fmaxf(ax1, bx1), ey1 = fmaxf(ay1, by1);
        float ew = fmaxf(ex1 - ex0, 0.f), eh = fmaxf(ey1 - ey0, 0.f);
        float earea = ew * eh;
        float giou = iou - (earea - uni) / earea;

        float ssum = 0.f;
        #pragma unroll
        for (int h = 0; h < NH; ++h) ssum += prow[h][q];   // coalesced in q

        costT[(b * NT + t) * NQ + q] = 5.0f * cost_bbox - 2.0f * ssum - 2.0f * giou;
    }
}

// ---------- Fallback stage 1 (ws too small): direct strided gather ----------
__global__ void cost_kernel_fb(const float* __restrict__ logits,
                               const float* __restrict__ pboxes,
                               const float* __restrict__ tboxes,
                               const int*   __restrict__ tlabels,
                               float* __restrict__ costT) {
    int id = blockIdx.x * blockDim.x + threadIdx.x;
    if (id >= BS * NT * NQ) return;
    int q = id % NQ;
    int t = (id / NQ) % NT;
    int b = id / (NQ * NT);

    const float* pb = pboxes + (b * NQ + q) * 4;
    const float* tb = tboxes + (b * NT + t) * 4;
    float px = pb[0], py = pb[1], pw = pb[2], ph = pb[3];
    float tx = tb[0], ty = tb[1], tw = tb[2], th = tb[3];

    float cost_bbox = fabsf(px - tx) + fabsf(py - ty) + fabsf(pw - tw) + fabsf(ph - th);

    float ax0 = px - 0.5f * pw, ay0 = py - 0.5f * ph;
    float ax1 = px + 0.5f * pw, ay1 = py + 0.5f * ph;
    float bx0 = tx - 0.5f * tw, by0 = ty - 0.5f * th;
    float bx1 = tx + 0.5f * tw, by1 = ty + 0.5f * th;
    float areaA = (ax1 - ax0) * (ay1 - ay0);
    float areaB = (bx1 - bx0) * (by1 - by0);
    float ltx = fmaxf(ax0, bx0), lty = fmaxf(ay0, by0);
    float rbx = fminf(ax1, bx1), rby = fminf(ay1, by1);
    float iw = fmaxf(rbx - ltx, 0.f), ih = fmaxf(rby - lty, 0.f);
    float inter = iw * ih;
    float uni = areaA + areaB - inter;
    float iou = inter / uni;
    float ex0 = fminf(ax0, bx0), ey0 = fminf(ay0, by0);
    float ex1 = fmaxf(ax1, bx1), ey1 = fmaxf(ay1, by1);
    float ew = fmaxf(ex1 - ex0, 0.f), eh = fmaxf(ey1 - ey0, 0.f);
    float earea = ew * eh;
    float giou = iou - (earea - uni) / earea;

    float ssum = 0.f;
    #pragma unroll
    for (int h = 0; h < NH; ++h) {
        int lab = tlabels[(h * BS + b) * NT + t];
        float x = logits[((h * BS + b) * NQ + q) * NC + lab];
        ssum += 1.0f / (1.0f + expf(-x));
    }

    costT[(b * NT + t) * NQ + q] = 5.0f * cost_bbox - 2.0f * ssum - 2.0f * giou;
}

// ---------- Stage 2: greedy(atomicMin) + Jacobi-ARR rounds + exact SAP tree ----------
// Invariants: duals feasible (c-u-v >= 0), assigned arcs tight. Jacobi rounds:
// scans are data-parallel; applies serial; v only DECREASES (d=c-v only increases)
// so a stored (m1,m2,j1) stays valid unless column j1 was taken this round (defer).
// Stale m2 is a lower bound -> u[i]=m2 smaller -> still feasible; arc still tight
// because v[j1] -= (m2-m1) uses the same stale m2. Tree stage (R3-verified) is exact.
__global__ __launch_bounds__(64) void lsa_kernel(const float* __restrict__ costT,
                                                 int* __restrict__ out) {
    const int b = blockIdx.x;
    const int lane = threadIdx.x;
    const float* cost = costT + b * NT * NQ;   // [t][q]

    __shared__ double2 pu[NQ + 1];     // {u[p[j]], p[j]} (p=0 -> free)
    __shared__ double u_s[NT + 1];
    __shared__ int way_s[NQ + 1];
    __shared__ int x_s[NT + 1];        // row -> col (0 = free)
    __shared__ int p_w[NQ + 1];        // greedy atomicMin arena
    __shared__ int touched[NQ + 1];    // round epoch per column
    __shared__ int jmin_s[NT];
    __shared__ int listA[NT], listB[NT];
    __shared__ double2 scan_mm[NT];    // {m1, m2}
    __shared__ int scan_j1[NT];
    __shared__ int r2c[NT];
    __shared__ int cnt_s;

    for (int j = lane; j <= NQ; j += 64) {
        pu[j] = make_double2(0.0, 0.0);
        p_w[j] = 0x7fffffff;
        touched[j] = -1;
    }
    if (lane == 0) cnt_s = 0;
    __syncthreads();

    // ---- row minima + argmin; greedy claim via atomicMin ----
    for (int base = 0; base < NT; base += 64) {
        int r = base + lane;
        if (r < NT) {
            const float4* row4 = (const float4*)(cost + (size_t)r * NQ);
            float m0 = INFINITY, m1f = INFINITY, m2f = INFINITY, m3f = INFINITY;
            int i0 = 0, i1 = 0, i2 = 0, i3 = 0;
            #pragma unroll 5
            for (int q4 = 0; q4 < NQ / 4; ++q4) {
                float4 cv = row4[q4];
                if (cv.x < m0)  { m0 = cv.x;  i0 = 4 * q4; }
                if (cv.y < m1f) { m1f = cv.y; i1 = 4 * q4 + 1; }
                if (cv.z < m2f) { m2f = cv.z; i2 = 4 * q4 + 2; }
                if (cv.w < m3f) { m3f = cv.w; i3 = 4 * q4 + 3; }
            }
            float mv = m0; int mj = i0;
            if (m1f < mv || (m1f == mv && i1 < mj)) { mv = m1f; mj = i1; }
            if (m2f < mv || (m2f == mv && i2 < mj)) { mv = m2f; mj = i2; }
            if (m3f < mv || (m3f == mv && i3 < mj)) { mv = m3f; mj = i3; }
            u_s[r + 1] = (double)mv;
            jmin_s[r] = mj;
            atomicMin(&p_w[mj + 1], r + 1);
        }
    }
    __syncthreads();

    // ---- resolve winners, build initial free list ----
    for (int base = 0; base < NT; base += 64) {
        int r = base + lane;
        if (r < NT) {
            int j = jmin_s[r] + 1;
            if (p_w[j] == r + 1) {
                x_s[r + 1] = j;
                pu[j] = make_double2(u_s[r + 1], (double)(r + 1));
            } else {
                x_s[r + 1] = 0;
                int pos = atomicAdd(&cnt_s, 1);
                listA[pos] = r + 1;
            }
        }
    }
    __syncthreads();
    int nfree = cnt_s;

    // lane-owned columns: slot k -> j = 1 + lane + 64*k
    double v[SLOTS], minv[SLOTS], ureg[SLOTS];
    int pof[SLOTS];
    #pragma unroll
    for (int k = 0; k < SLOTS; ++k) { v[k] = 0.0; ureg[k] = 0.0; pof[k] = 0; }
    const unsigned invalid = (lane < 4) ? 0u : (1u << 14);   // slot 14: j=897..960
    double u_c0 = 0.0;

    // ---- Jacobi-ARR rounds ----
    int* curL = listA;
    int* nxtL = listB;
    for (int round = 0; round < MAXROUNDS && nfree > 0; ++round) {
        // SCAN phase: data-parallel row scans (pairs for load pipelining)
        for (int idx = 0; idx < nfree; idx += 2) {
            const int iA = curL[idx];
            const bool hasB = (idx + 1) < nfree;
            const int iB = hasB ? curL[idx + 1] : iA;
            const float* rowA = cost + (size_t)(iA - 1) * NQ;
            const float* rowB = cost + (size_t)(iB - 1) * NQ;
            float cA[SLOTS], cB[SLOTS];
            #pragma unroll
            for (int k = 0; k < SLOTS - 1; ++k) cA[k] = rowA[lane + 64 * k];
            cA[SLOTS - 1] = (lane < 4) ? rowA[lane + 64 * (SLOTS - 1)] : 0.0f;
            #pragma unroll
            for (int k = 0; k < SLOTS - 1; ++k) cB[k] = rowB[lane + 64 * k];
            cB[SLOTS - 1] = (lane < 4) ? rowB[lane + 64 * (SLOTS - 1)] : 0.0f;

            {   // scan + butterfly A
                double m1 = INFINITY, m2 = INFINITY; int j1 = 2048;
                #pragma unroll
                for (int k = 0; k < SLOTS; ++k) {
                    if (!((invalid >> k) & 1u)) {
                        int j = 1 + lane + 64 * k;
                        double d = (double)cA[k] - v[k];
                        if (d < m1 || (d == m1 && j < j1)) { m2 = m1; m1 = d; j1 = j; }
                        else if (d < m2) m2 = d;
                    }
                }
                #pragma unroll
                for (int off = 1; off < 64; off <<= 1) {
                    double om1 = __shfl_xor(m1, off);
                    double om2 = __shfl_xor(m2, off);
                    int oj1 = __shfl_xor(j1, off);
                    if (om1 < m1 || (om1 == m1 && oj1 < j1)) { m2 = fmin(m1, om2); m1 = om1; j1 = oj1; }
                    else m2 = fmin(m2, om1);
                }
                if (lane == 0) { scan_mm[idx] = make_double2(m1, m2); scan_j1[idx] = j1; }
            }
            if (hasB) {   // scan + butterfly B
                double m1 = INFINITY, m2 = INFINITY; int j1 = 2048;
                #pragma unroll
                for (int k = 0; k < SLOTS; ++k) {
                    if (!((invalid >> k) & 1u)) {
                        int j = 1 + lane + 64 * k;
                        double d = (double)cB[k] - v[k];
                        if (d < m1 || (d == m1 && j < j1)) { m2 = m1; m1 = d; j1 = j; }
                        else if (d < m2) m2 = d;
                    }
                }
                #pragma unroll
                for (int off = 1; off < 64; off <<= 1) {
                    double om1 = __shfl_xor(m1, off);
                    double om2 = __shfl_xor(m2, off);
                    int oj1 = __shfl_xor(j1, off);
                    if (om1 < m1 || (om1 == m1 && oj1 < j1)) { m2 = fmin(m1, om2); m1 = om1; j1 = oj1; }
                    else m2 = fmin(m2, om1);
                }
                if (lane == 0) { scan_mm[idx + 1] = make_double2(m1, m2); scan_j1[idx + 1] = j1; }
            }
        }

        // APPLY phase: wave-uniform serial; v updates on owner lane
        int nfree2 = 0;
        for (int idx = 0; idx < nfree; ++idx) {
            int i = curL[idx];
            double2 mm = scan_mm[idx];     // broadcast LDS reads (wave-uniform values)
            int j1 = scan_j1[idx];
            if (touched[j1] == round) {    // column taken this round -> stale argmin, defer
                if (lane == 0) nxtL[nfree2] = i;
                ++nfree2;
                continue;
            }
            int k1 = (int)pu[j1].y;
            if (lane == 0) touched[j1] = round;
            int sl = (j1 - 1) >> 6;
            if (lane == ((j1 - 1) & 63)) {
                double dv = mm.y - mm.x;
                #pragma unroll
                for (int k = 0; k < SLOTS; ++k) if (k == sl) v[k] -= dv;
            }
            if (lane == 0) {
                u_s[i] = mm.y;
                pu[j1] = make_double2(mm.y, (double)i);
                x_s[i] = j1;
                if (k1) x_s[k1] = 0;
            }
            if (k1) {                      // dethroned row re-enters next round
                if (lane == 0) nxtL[nfree2] = k1;
                ++nfree2;
            }
        }
        int* tmp = curL; curL = nxtL; nxtL = tmp;
        nfree = nfree2;
    }
    __syncthreads();

    // ---- exact SAP tree stage for leftovers (R3-verified structure) ----
    for (int ii = 0; ii < nfree; ++ii) {
        const int i = curL[ii];
        #pragma unroll
        for (int k = 0; k < SLOTS; ++k) minv[k] = INFINITY;
        unsigned used = invalid;
        int j0 = 0;
        int i0 = i;
        double u_i0 = u_s[i];
        int guard = 0;

        while (guard++ < MAXTREE) {
            if (j0 != 0) {
                if (lane == ((j0 - 1) & 63)) {
                    int slot = (j0 - 1) >> 6;
                    used |= (1u << slot);
                    #pragma unroll
                    for (int k = 0; k < SLOTS; ++k)
                        if (slot == k) { pof[k] = i0; ureg[k] = u_i0; }
                }
            } else {
                if (lane == 0) u_c0 = u_i0;
            }

            const float* crow = cost + (size_t)(i0 - 1) * NQ;
            float c[SLOTS];
            #pragma unroll
            for (int k = 0; k < SLOTS - 1; ++k) c[k] = crow[lane + 64 * k];
            c[SLOTS - 1] = (lane < 4) ? crow[lane + 64 * (SLOTS - 1)] : 0.0f;

            double bv = INFINITY;
            int bj = 2048;
            #pragma unroll
            for (int k = 0; k < SLOTS; ++k) {
                if (!((used >> k) & 1u)) {
                    int j = 1 + lane + 64 * k;
                    double cur = ((double)c[k] - u_i0) - v[k];
                    if (cur < minv[k]) { minv[k] = cur; way_s[j] = j0; }
                    if (minv[k] < bv) { bv = minv[k]; bj = j; }
                }
            }
            #pragma unroll
            for (int off = 1; off < 64; off <<= 1) {
                double ov = __shfl_xor(bv, off);
                int oj = __shfl_xor(bj, off);
                if (ov < bv || (ov == bv && oj < bj)) { bv = ov; bj = oj; }
            }
            const double delta = bv;

            #pragma unroll
            for (int k = 0; k < SLOTS; ++k) {
                if ((used >> k) & 1u) { ureg[k] += delta; v[k] -= delta; }
                else                  { minv[k] -= delta; }
            }
            if (lane == 0) u_c0 += delta;

            double2 t = pu[bj];            // one b128: {u[p[bj]], p[bj]}
            j0 = bj;
            i0 = (int)t.y;
            u_i0 = t.x;
            if (i0 == 0) break;
        }

        __syncthreads();
        #pragma unroll
        for (int k = 0; k < SLOTS; ++k) {
            if (((used >> k) & 1u) && !((invalid >> k) & 1u)) {
                int j = 1 + lane + 64 * k;
                u_s[pof[k]] = ureg[k];
                pu[j] = make_double2(ureg[k], (double)pof[k]);
            }
        }
        __syncthreads();
        if (lane == 0) {
            u_s[i] = u_c0;
            int j = j0;
            while (j) {
                int jw = way_s[j];
                double2 t2 = (jw == 0) ? make_double2(u_c0, (double)i) : pu[jw];
                pu[j] = t2;
                j = jw;
            }
        }
        __syncthreads();
    }

    // ---- row2col + stable-argsort ranks ----
    for (int j = 1 + lane; j <= NQ; j += 64) {
        int pi = (int)pu[j].y;
        if (pi > 0) r2c[pi - 1] = j - 1;
    }
    __syncthreads();
    for (int t = lane; t < NT; t += 64) {
        int ccol = r2c[t];
        int rank = 0;
        for (int tt = 0; tt < NT; ++tt) rank += (r2c[tt] < ccol) ? 1 : 0;
        out[b * 2 * NT + rank] = ccol;         // out[b,0,rank] = pred idx
        out[b * 2 * NT + NT + rank] = t;       // out[b,1,rank] = target idx
    }
}

extern "C" void kernel_launch(void* const* d_in, const int* in_sizes, int n_in,
                              void* d_out, int out_size, void* d_ws, size_t ws_size,
                              hipStream_t stream) {
    const float* logits  = (const float*)d_in[0];  // (7,16,900,16)
    const float* pboxes  = (const float*)d_in[1];  // (16,900,4)
    const float* tboxes  = (const float*)d_in[2];  // (16,100,4)
    const int*   tlabels = (const int*)d_in[3];    // (7,16,100)
    int* out = (int*)d_out;                        // (16,2,100) int32
    float* costT = (float*)d_ws;                   // 1,440,000 floats = 5.76 MB

    const size_t costT_elems  = (size_t)BS * NT * NQ;
    const size_t probsT_elems = (size_t)NH * BS * NC * NQ;
    const size_t need = (costT_elems + probsT_elems) * sizeof(float);

    if (ws_size >= need) {
        float* probsT = costT + costT_elems;
        sig_transpose_kernel<<<NH * BS, 256, 0, stream>>>(logits, probsT);
        cost_kernel_bt<<<BS * NT, 256, 0, stream>>>((const float4*)pboxes,
                                                    (const float4*)tboxes, tlabels, probsT, costT);
    } else {
        const int total = BS * NT * NQ;
        cost_kernel_fb<<<(total + 255) / 256, 256, 0, stream>>>(logits, pboxes, tboxes, tlabels, costT);
    }
    lsa_kernel<<<BS, 64, 0, stream>>>(costT, out);
}

// Round 8
// 125.039 us; speedup vs baseline: 1.1778x; 1.0705x over previous
//
#include <hip/hip_runtime.h>
#include <hip/hip_bf16.h>
#include <math.h>

#define NQ 900
#define NT 100
#define BS 16
#define NH 7
#define NC 16
#define SLOTS 15      // 64 lanes * 15 slots = 960 >= 900 columns
#define MAXTREE 8192  // per-phase tree guard (no hang on bug)

// ---------- Stage 1a: sigmoid + transpose probs: [h,b,q,c] -> [h,b,c,q] ----------
__global__ __launch_bounds__(256) void sig_transpose_kernel(const float* __restrict__ logits,
                                                            float* __restrict__ probsT) {
    const int hb = blockIdx.x;                       // 0..NH*BS-1
    const float* src = logits + (size_t)hb * NQ * NC;
    float* dst = probsT + (size_t)hb * NC * NQ;
    __shared__ float tile[NC][NQ + 1];
    for (int e = threadIdx.x; e < NQ * NC; e += 256) {
        int q = e >> 4, c = e & 15;
        float x = src[e];
        tile[c][q] = 1.0f / (1.0f + expf(-x));       // same formula as R0 -> identical costT
    }
    __syncthreads();
    for (int c = 0; c < NC; ++c)
        for (int q = threadIdx.x; q < NQ; q += 256)
            dst[c * NQ + q] = tile[c][q];
}

// ---------- Stage 1b: cost matrix (transposed [b][t][q]); one block per (b,t) ----------
__global__ __launch_bounds__(256) void cost_kernel_bt(const float4* __restrict__ pboxes4,
                                                      const float4* __restrict__ tboxes4,
                                                      const int*    __restrict__ tlabels,
                                                      const float*  __restrict__ probsT,
                                                      float* __restrict__ costT) {
    const int bt = blockIdx.x;
    const int b = bt / NT, t = bt % NT;

    const float* prow[NH];
    #pragma unroll
    for (int h = 0; h < NH; ++h) {
        int lab = tlabels[(h * BS + b) * NT + t];          // uniform -> scalar load
        prow[h] = probsT + (size_t)((h * BS + b) * NC + lab) * NQ;
    }

    float4 tb = tboxes4[b * NT + t];
    float tx = tb.x, ty = tb.y, tw = tb.z, th = tb.w;
    float bx0 = tx - 0.5f * tw, by0 = ty - 0.5f * th;
    float bx1 = tx + 0.5f * tw, by1 = ty + 0.5f * th;
    float areaB = (bx1 - bx0) * (by1 - by0);

    for (int q = threadIdx.x; q < NQ; q += 256) {
        float4 pb = pboxes4[b * NQ + q];
        float px = pb.x, py = pb.y, pw = pb.z, ph = pb.w;

        float cost_bbox = fabsf(px - tx) + fabsf(py - ty) + fabsf(pw - tw) + fabsf(ph - th);

        float ax0 = px - 0.5f * pw, ay0 = py - 0.5f * ph;
        float ax1 = px + 0.5f * pw, ay1 = py + 0.5f * ph;
        float areaA = (ax1 - ax0) * (ay1 - ay0);
        float ltx = fmaxf(ax0, bx0), lty = fmaxf(ay0, by0);
        float rbx = fminf(ax1, bx1), rby = fminf(ay1, by1);
        float iw = fmaxf(rbx - ltx, 0.f), ih = fmaxf(rby - lty, 0.f);
        float inter = iw * ih;
        float uni = areaA + areaB - inter;
        float iou = inter / uni;
        float ex0 = fminf(ax0, bx0), ey0 = fminf(ay0, by0);
        float ex1 = fmaxf(ax1, bx1), ey1 = fmaxf(ay1, by1);
        float ew = fmaxf(ex1 - ex0, 0.f), eh = fmaxf(ey1 - ey0, 0.f);
        float earea = ew * eh;
        float giou = iou - (earea - uni) / earea;

        float ssum = 0.f;
        #pragma unroll
        for (int h = 0; h < NH; ++h) ssum += prow[h][q];   // coalesced in q

        costT[(b * NT + t) * NQ + q] = 5.0f * cost_bbox - 2.0f * ssum - 2.0f * giou;
    }
}

// ---------- Fallback stage 1 (ws too small): direct strided gather ----------
__global__ void cost_kernel_fb(const float* __restrict__ logits,
                               const float* __restrict__ pboxes,
                               const float* __restrict__ tboxes,
                               const int*   __restrict__ tlabels,
                               float* __restrict__ costT) {
    int id = blockIdx.x * blockDim.x + threadIdx.x;
    if (id >= BS * NT * NQ) return;
    int q = id % NQ;
    int t = (id / NQ) % NT;
    int b = id / (NQ * NT);

    const float* pb = pboxes + (b * NQ + q) * 4;
    const float* tb = tboxes + (b * NT + t) * 4;
    float px = pb[0], py = pb[1], pw = pb[2], ph = pb[3];
    float tx = tb[0], ty = tb[1], tw = tb[2], th = tb[3];

    float cost_bbox = fabsf(px - tx) + fabsf(py - ty) + fabsf(pw - tw) + fabsf(ph - th);

    float ax0 = px - 0.5f * pw, ay0 = py - 0.5f * ph;
    float ax1 = px + 0.5f * pw, ay1 = py + 0.5f * ph;
    float bx0 = tx - 0.5f * tw, by0 = ty - 0.5f * th;
    float bx1 = tx + 0.5f * tw, by1 = ty + 0.5f * th;
    float areaA = (ax1 - ax0) * (ay1 - ay0);
    float areaB = (bx1 - bx0) * (by1 - by0);
    float ltx = fmaxf(ax0, bx0), lty = fmaxf(ay0, by0);
    float rbx = fminf(ax1, bx1), rby = fminf(ay1, by1);
    float iw = fmaxf(rbx - ltx, 0.f), ih = fmaxf(rby - lty, 0.f);
    float inter = iw * ih;
    float uni = areaA + areaB - inter;
    float iou = inter / uni;
    float ex0 = fminf(ax0, bx0), ey0 = fminf(ay0, by0);
    float ex1 = fmaxf(ax1, bx1), ey1 = fmaxf(ay1, by1);
    float ew = fmaxf(ex1 - ex0, 0.f), eh = fmaxf(ey1 - ey0, 0.f);
    float earea = ew * eh;
    float giou = iou - (earea - uni) / earea;

    float ssum = 0.f;
    #pragma unroll
    for (int h = 0; h < NH; ++h) {
        int lab = tlabels[(h * BS + b) * NT + t];
        float x = logits[((h * BS + b) * NQ + q) * NC + lab];
        ssum += 1.0f / (1.0f + expf(-x));
    }

    costT[(b * NT + t) * NQ + q] = 5.0f * cost_bbox - 2.0f * ssum - 2.0f * giou;
}

// ---------- Stage 2: JV LSA, v=0 init (REQUIRED for rectangular problems) ----------
// R5/R6 lesson: column reduction (v=colmin) breaks rectangular LSA -- complementary
// slackness needs v[j]=0 on unmatched columns. So: v=0, u[i]=rowmin (exact f32->f64),
// greedy claim of row-argmin columns (all tight arcs), exact SAP tree for the rest.
// Duals feasible + assigned arcs tight + v=0 on unmatched -> unique optimal matching
// == reference's. All f64 comparisons exact; numpy argmin tie-break (smallest j).
__global__ __launch_bounds__(64) void lsa_kernel(const float* __restrict__ costT,
                                                 int* __restrict__ out) {
    const int b = blockIdx.x;
    const int lane = threadIdx.x;
    const float* cost = costT + b * NT * NQ;   // [t][q]

    __shared__ double2 pu[NQ + 1];     // {u[p[j]], p[j]} (p=0 -> free)
    __shared__ double u_s[NT + 1];
    __shared__ int way_s[NQ + 1];
    __shared__ int p_w[NQ + 1];        // greedy atomicMin arena
    __shared__ int jmin_s[NT];
    __shared__ int listA[NT];
    __shared__ int r2c[NT];
    __shared__ int cnt_s;

    for (int j = lane; j <= NQ; j += 64) {
        pu[j] = make_double2(0.0, 0.0);
        p_w[j] = 0x7fffffff;
    }
    __syncthreads();

    // ---- row minima + argmin (v = 0); greedy claim via atomicMin ----
    bool lostA = false, lostB = false;
    #pragma unroll
    for (int pass = 0; pass < 2; ++pass) {
        int r = pass * 64 + lane;
        if (r < NT) {
            const float4* row4 = (const float4*)(cost + (size_t)r * NQ);
            float m0 = INFINITY, m1f = INFINITY, m2f = INFINITY, m3f = INFINITY;
            int i0 = 0, i1 = 0, i2 = 0, i3 = 0;
            #pragma unroll 5
            for (int q4 = 0; q4 < NQ / 4; ++q4) {
                float4 cv = row4[q4];
                if (cv.x < m0)  { m0 = cv.x;  i0 = 4 * q4; }
                if (cv.y < m1f) { m1f = cv.y; i1 = 4 * q4 + 1; }
                if (cv.z < m2f) { m2f = cv.z; i2 = 4 * q4 + 2; }
                if (cv.w < m3f) { m3f = cv.w; i3 = 4 * q4 + 3; }
            }
            float mv = m0; int mj = i0;
            if (m1f < mv || (m1f == mv && i1 < mj)) { mv = m1f; mj = i1; }
            if (m2f < mv || (m2f == mv && i2 < mj)) { mv = m2f; mj = i2; }
            if (m3f < mv || (m3f == mv && i3 < mj)) { mv = m3f; mj = i3; }
            u_s[r + 1] = (double)mv;    // u = rowmin (exact); v stays 0
            jmin_s[r] = mj;
            atomicMin(&p_w[mj + 1], r + 1);
        }
    }
    __syncthreads();

    // resolve winners (deterministic: smallest row wins each contested column)
    {
        int rA = lane;
        int j = jmin_s[rA] + 1;
        if (p_w[j] == rA + 1) pu[j] = make_double2(u_s[rA + 1], (double)(rA + 1));
        else lostA = true;
    }
    if (lane < NT - 64) {
        int rB = 64 + lane;
        int j = jmin_s[rB] + 1;
        if (p_w[j] == rB + 1) pu[j] = make_double2(u_s[rB + 1], (double)(rB + 1));
        else lostB = true;
    }
    // deterministic ascending free-row list via ballot bit-scan
    unsigned long long mA = __ballot(lostA);
    unsigned long long mB = __ballot(lostB);
    if (lane == 0) {
        int n = 0;
        unsigned long long m = mA;
        while (m) { int l = __ffsll((long long)m) - 1; listA[n++] = l + 1; m &= m - 1; }
        m = mB;
        while (m) { int l = __ffsll((long long)m) - 1; listA[n++] = 64 + l + 1; m &= m - 1; }
        cnt_s = n;
    }
    __syncthreads();
    const int nfree = cnt_s;

    // lane-owned columns: slot k -> j = 1 + lane + 64*k
    double v[SLOTS], minv[SLOTS], ureg[SLOTS];
    int pof[SLOTS];
    #pragma unroll
    for (int k = 0; k < SLOTS; ++k) { v[k] = 0.0; ureg[k] = 0.0; pof[k] = 0; }
    const unsigned invalid = (lane < 4) ? 0u : (1u << 14);   // slot 14: j=897..960
    double u_c0 = 0.0;

    // ---- exact SAP tree stage (R2/R4-verified structure) ----
    for (int ii = 0; ii < nfree; ++ii) {
        const int i = listA[ii];
        #pragma unroll
        for (int k = 0; k < SLOTS; ++k) minv[k] = INFINITY;
        unsigned used = invalid;
        int j0 = 0;
        int i0 = i;
        double u_i0 = u_s[i];
        int guard = 0;

        while (guard++ < MAXTREE) {
            // stage A: mark j0 used (owner lane records row + running u)
            if (j0 != 0) {
                if (lane == ((j0 - 1) & 63)) {
                    int slot = (j0 - 1) >> 6;
                    used |= (1u << slot);
                    #pragma unroll
                    for (int k = 0; k < SLOTS; ++k)
                        if (slot == k) { pof[k] = i0; ureg[k] = u_i0; }
                }
            } else {
                if (lane == 0) u_c0 = u_i0;
            }

            // row fetch (L2-resident; issued early)
            const float* crow = cost + (size_t)(i0 - 1) * NQ;
            float c[SLOTS];
            #pragma unroll
            for (int k = 0; k < SLOTS - 1; ++k) c[k] = crow[lane + 64 * k];
            c[SLOTS - 1] = (lane < 4) ? crow[lane + 64 * (SLOTS - 1)] : 0.0f;

            // stage B: scan free columns (cur = (c - u) - v, R2's exact ordering)
            double bv = INFINITY;
            int bj = 2048;
            #pragma unroll
            for (int k = 0; k < SLOTS; ++k) {
                if (!((used >> k) & 1u)) {
                    int j = 1 + lane + 64 * k;
                    double cur = ((double)c[k] - u_i0) - v[k];
                    if (cur < minv[k]) { minv[k] = cur; way_s[j] = j0; }
                    if (minv[k] < bv) { bv = minv[k]; bj = j; }
                }
            }
            // EXACT 3-value butterfly argmin over 64 lanes, tie -> smaller j
            #pragma unroll
            for (int off = 1; off < 64; off <<= 1) {
                double ov = __shfl_xor(bv, off);
                int oj = __shfl_xor(bj, off);
                if (ov < bv || (ov == bv && oj < bj)) { bv = ov; bj = oj; }
            }
            const double delta = bv;

            // advance-read issued NOW so stage D's VALU work hides the LDS latency
            double2 t = pu[bj];

            // stage D: dual update (register-resident)
            #pragma unroll
            for (int k = 0; k < SLOTS; ++k) {
                minv[k] -= delta;              // harmless for used slots (never read)
                if ((used >> k) & 1u) { ureg[k] += delta; v[k] -= delta; }
            }
            if (lane == 0) u_c0 += delta;

            j0 = bj;
            i0 = (int)t.y;
            u_i0 = t.x;
            if (i0 == 0) break;
        }

        __syncthreads();
        // owner writebacks: u of rows sitting on used columns
        #pragma unroll
        for (int k = 0; k < SLOTS; ++k) {
            if (((used >> k) & 1u) && !((invalid >> k) & 1u)) {
                int j = 1 + lane + 64 * k;
                u_s[pof[k]] = ureg[k];
                pu[j] = make_double2(ureg[k], (double)pof[k]);
            }
        }
        __syncthreads();
        if (lane == 0) {
            u_s[i] = u_c0;
            int j = j0;
            while (j) {
                int jw = way_s[j];
                double2 t2 = (jw == 0) ? make_double2(u_c0, (double)i) : pu[jw];
                pu[j] = t2;
                j = jw;
            }
        }
        __syncthreads();
    }

    // ---- row2col + stable-argsort ranks ----
    for (int j = 1 + lane; j <= NQ; j += 64) {
        int pi = (int)pu[j].y;
        if (pi > 0) r2c[pi - 1] = j - 1;
    }
    __syncthreads();
    for (int t = lane; t < NT; t += 64) {
        int ccol = r2c[t];
        int rank = 0;
        for (int tt = 0; tt < NT; ++tt) rank += (r2c[tt] < ccol) ? 1 : 0;
        out[b * 2 * NT + rank] = ccol;         // out[b,0,rank] = pred idx
        out[b * 2 * NT + NT + rank] = t;       // out[b,1,rank] = target idx
    }
}

extern "C" void kernel_launch(void* const* d_in, const int* in_sizes, int n_in,
                              void* d_out, int out_size, void* d_ws, size_t ws_size,
                              hipStream_t stream) {
    const float* logits  = (const float*)d_in[0];  // (7,16,900,16)
    const float* pboxes  = (const float*)d_in[1];  // (16,900,4)
    const float* tboxes  = (const float*)d_in[2];  // (16,100,4)
    const int*   tlabels = (const int*)d_in[3];    // (7,16,100)
    int* out = (int*)d_out;                        // (16,2,100) int32
    float* costT = (float*)d_ws;                   // 1,440,000 floats = 5.76 MB

    const size_t costT_elems  = (size_t)BS * NT * NQ;
    const size_t probsT_elems = (size_t)NH * BS * NC * NQ;
    const size_t need = (costT_elems + probsT_elems) * sizeof(float);

    if (ws_size >= need) {
        float* probsT = costT + costT_elems;
        sig_transpose_kernel<<<NH * BS, 256, 0, stream>>>(logits, probsT);
        cost_kernel_bt<<<BS * NT, 256, 0, stream>>>((const float4*)pboxes,
                                                    (const float4*)tboxes, tlabels, probsT, costT);
    } else {
        const int total = BS * NT * NQ;
        cost_kernel_fb<<<(total + 255) / 256, 256, 0, stream>>>(logits, pboxes, tboxes, tlabels, costT);
    }
    lsa_kernel<<<BS, 64, 0, stream>>>(costT, out);
}

// Round 9
// 120.501 us; speedup vs baseline: 1.2222x; 1.0377x over previous
//
#include <hip/hip_runtime.h>
#include <hip/hip_bf16.h>
#include <math.h>

#define NQ 900
#define NT 100
#define BS 16
#define NH 7
#define NC 16
#define NSLOT 16      // 4 chunks (kc) x 4 elems (e); column idx = 4*lane + 256*kc + e
#define MAXTREE 8192  // per-phase tree guard (no hang on bug)

// ---------- Stage 1a: sigmoid + transpose probs: [h,b,q,c] -> [h,b,c,q] ----------
__global__ __launch_bounds__(256) void sig_transpose_kernel(const float* __restrict__ logits,
                                                            float* __restrict__ probsT) {
    const int hb = blockIdx.x;                       // 0..NH*BS-1
    const float* src = logits + (size_t)hb * NQ * NC;
    float* dst = probsT + (size_t)hb * NC * NQ;
    __shared__ float tile[NC][NQ + 1];
    for (int e = threadIdx.x; e < NQ * NC; e += 256) {
        int q = e >> 4, c = e & 15;
        float x = src[e];
        tile[c][q] = 1.0f / (1.0f + expf(-x));       // same formula as R0 -> identical costT
    }
    __syncthreads();
    for (int c = 0; c < NC; ++c)
        for (int q = threadIdx.x; q < NQ; q += 256)
            dst[c * NQ + q] = tile[c][q];
}

// ---------- Stage 1b: cost matrix (transposed [b][t][q]); one block per (b,t) ----------
__global__ __launch_bounds__(256) void cost_kernel_bt(const float4* __restrict__ pboxes4,
                                                      const float4* __restrict__ tboxes4,
                                                      const int*    __restrict__ tlabels,
                                                      const float*  __restrict__ probsT,
                                                      float* __restrict__ costT) {
    const int bt = blockIdx.x;
    const int b = bt / NT, t = bt % NT;

    const float* prow[NH];
    #pragma unroll
    for (int h = 0; h < NH; ++h) {
        int lab = tlabels[(h * BS + b) * NT + t];          // uniform -> scalar load
        prow[h] = probsT + (size_t)((h * BS + b) * NC + lab) * NQ;
    }

    float4 tb = tboxes4[b * NT + t];
    float tx = tb.x, ty = tb.y, tw = tb.z, th = tb.w;
    float bx0 = tx - 0.5f * tw, by0 = ty - 0.5f * th;
    float bx1 = tx + 0.5f * tw, by1 = ty + 0.5f * th;
    float areaB = (bx1 - bx0) * (by1 - by0);

    for (int q = threadIdx.x; q < NQ; q += 256) {
        float4 pb = pboxes4[b * NQ + q];
        float px = pb.x, py = pb.y, pw = pb.z, ph = pb.w;

        float cost_bbox = fabsf(px - tx) + fabsf(py - ty) + fabsf(pw - tw) + fabsf(ph - th);

        float ax0 = px - 0.5f * pw, ay0 = py - 0.5f * ph;
        float ax1 = px + 0.5f * pw, ay1 = py + 0.5f * ph;
        float areaA = (ax1 - ax0) * (ay1 - ay0);
        float ltx = fmaxf(ax0, bx0), lty = fmaxf(ay0, by0);
        float rbx = fminf(ax1, bx1), rby = fminf(ay1, by1);
        float iw = fmaxf(rbx - ltx, 0.f), ih = fmaxf(rby - lty, 0.f);
        float inter = iw * ih;
        float uni = areaA + areaB - inter;
        float iou = inter / uni;
        float ex0 = fminf(ax0, bx0), ey0 = fminf(ay0, by0);
        float ex1 = fmaxf(ax1, bx1), ey1 = fmaxf(ay1, by1);
        float ew = fmaxf(ex1 - ex0, 0.f), eh = fmaxf(ey1 - ey0, 0.f);
        float earea = ew * eh;
        float giou = iou - (earea - uni) / earea;

        float ssum = 0.f;
        #pragma unroll
        for (int h = 0; h < NH; ++h) ssum += prow[h][q];   // coalesced in q

        costT[(b * NT + t) * NQ + q] = 5.0f * cost_bbox - 2.0f * ssum - 2.0f * giou;
    }
}

// ---------- Fallback stage 1 (ws too small): direct strided gather ----------
__global__ void cost_kernel_fb(const float* __restrict__ logits,
                               const float* __restrict__ pboxes,
                               const float* __restrict__ tboxes,
                               const int*   __restrict__ tlabels,
                               float* __restrict__ costT) {
    int id = blockIdx.x * blockDim.x + threadIdx.x;
    if (id >= BS * NT * NQ) return;
    int q = id % NQ;
    int t = (id / NQ) % NT;
    int b = id / (NQ * NT);

    const float* pb = pboxes + (b * NQ + q) * 4;
    const float* tb = tboxes + (b * NT + t) * 4;
    float px = pb[0], py = pb[1], pw = pb[2], ph = pb[3];
    float tx = tb[0], ty = tb[1], tw = tb[2], th = tb[3];

    float cost_bbox = fabsf(px - tx) + fabsf(py - ty) + fabsf(pw - tw) + fabsf(ph - th);

    float ax0 = px - 0.5f * pw, ay0 = py - 0.5f * ph;
    float ax1 = px + 0.5f * pw, ay1 = py + 0.5f * ph;
    float bx0 = tx - 0.5f * tw, by0 = ty - 0.5f * th;
    float bx1 = tx + 0.5f * tw, by1 = ty + 0.5f * th;
    float areaA = (ax1 - ax0) * (ay1 - ay0);
    float areaB = (bx1 - bx0) * (by1 - by0);
    float ltx = fmaxf(ax0, bx0), lty = fmaxf(ay0, by0);
    float rbx = fminf(ax1, bx1), rby = fminf(ay1, by1);
    float iw = fmaxf(rbx - ltx, 0.f), ih = fmaxf(rby - lty, 0.f);
    float inter = iw * ih;
    float uni = areaA + areaB - inter;
    float iou = inter / uni;
    float ex0 = fminf(ax0, bx0), ey0 = fminf(ay0, by0);
    float ex1 = fmaxf(ax1, bx1), ey1 = fmaxf(ay1, by1);
    float ew = fmaxf(ex1 - ex0, 0.f), eh = fmaxf(ey1 - ey0, 0.f);
    float earea = ew * eh;
    float giou = iou - (earea - uni) / earea;

    float ssum = 0.f;
    #pragma unroll
    for (int h = 0; h < NH; ++h) {
        int lab = tlabels[(h * BS + b) * NT + t];
        float x = logits[((h * BS + b) * NQ + q) * NC + lab];
        ssum += 1.0f / (1.0f + expf(-x));
    }

    costT[(b * NT + t) * NQ + q] = 5.0f * cost_bbox - 2.0f * ssum - 2.0f * giou;
}

// ---------- Stage 2: JV LSA, v=0 init (rectangular-correct), exact SAP tree ----------
// R7-passing structure. Changes (both decision-preserving):
//  * float4 column layout: lane owns idx = 4*lane + 256*kc + e (4x dwordx4 row fetch)
//  * value-only exact f64 min butterfly; winner lane via ballot; delta = exact min.
//    (cross-lane EXACT-tie column choice may differ from numpy -- measure-zero and
//     protected by optimum uniqueness; delta itself is exact so duals stay exact.)
__global__ __launch_bounds__(64) void lsa_kernel(const float* __restrict__ costT,
                                                 int* __restrict__ out) {
    const int b = blockIdx.x;
    const int lane = threadIdx.x;
    const float* cost = costT + b * NT * NQ;   // [t][q]

    __shared__ double2 pu[NQ + 1];     // {u[p[j]], p[j]} (p=0 -> free)
    __shared__ double u_s[NT + 1];
    __shared__ int way_s[NQ + 1];
    __shared__ int p_w[NQ + 1];        // greedy atomicMin arena
    __shared__ int jmin_s[NT];
    __shared__ int listA[NT];
    __shared__ int r2c[NT];
    __shared__ int cnt_s;

    for (int j = lane; j <= NQ; j += 64) {
        pu[j] = make_double2(0.0, 0.0);
        p_w[j] = 0x7fffffff;
    }
    __syncthreads();

    // ---- row minima + argmin (v = 0); greedy claim via atomicMin ----
    bool lostA = false, lostB = false;
    #pragma unroll
    for (int pass = 0; pass < 2; ++pass) {
        int r = pass * 64 + lane;
        if (r < NT) {
            const float4* row4 = (const float4*)(cost + (size_t)r * NQ);
            float m0 = INFINITY, m1f = INFINITY, m2f = INFINITY, m3f = INFINITY;
            int i0 = 0, i1 = 0, i2 = 0, i3 = 0;
            #pragma unroll 5
            for (int q4 = 0; q4 < NQ / 4; ++q4) {
                float4 cv = row4[q4];
                if (cv.x < m0)  { m0 = cv.x;  i0 = 4 * q4; }
                if (cv.y < m1f) { m1f = cv.y; i1 = 4 * q4 + 1; }
                if (cv.z < m2f) { m2f = cv.z; i2 = 4 * q4 + 2; }
                if (cv.w < m3f) { m3f = cv.w; i3 = 4 * q4 + 3; }
            }
            float mv = m0; int mj = i0;
            if (m1f < mv || (m1f == mv && i1 < mj)) { mv = m1f; mj = i1; }
            if (m2f < mv || (m2f == mv && i2 < mj)) { mv = m2f; mj = i2; }
            if (m3f < mv || (m3f == mv && i3 < mj)) { mv = m3f; mj = i3; }
            u_s[r + 1] = (double)mv;    // u = rowmin (exact); v stays 0
            jmin_s[r] = mj;
            atomicMin(&p_w[mj + 1], r + 1);
        }
    }
    __syncthreads();

    // resolve winners (deterministic: smallest row wins each contested column)
    {
        int rA = lane;
        int j = jmin_s[rA] + 1;
        if (p_w[j] == rA + 1) pu[j] = make_double2(u_s[rA + 1], (double)(rA + 1));
        else lostA = true;
    }
    if (lane < NT - 64) {
        int rB = 64 + lane;
        int j = jmin_s[rB] + 1;
        if (p_w[j] == rB + 1) pu[j] = make_double2(u_s[rB + 1], (double)(rB + 1));
        else lostB = true;
    }
    // deterministic ascending free-row list via ballot bit-scan
    unsigned long long mA = __ballot(lostA);
    unsigned long long mB = __ballot(lostB);
    if (lane == 0) {
        int n = 0;
        unsigned long long m = mA;
        while (m) { int l = __ffsll((unsigned long long)m) - 1; listA[n++] = l + 1; m &= m - 1; }
        m = mB;
        while (m) { int l = __ffsll((unsigned long long)m) - 1; listA[n++] = 64 + l + 1; m &= m - 1; }
        cnt_s = n;
    }
    __syncthreads();
    const int nfree = cnt_s;

    // lane-owned columns: slot s = 4*kc + e -> idx = 4*lane + 256*kc + e, j = idx+1
    double v[NSLOT], minv[NSLOT], ureg[NSLOT];
    int pof[NSLOT];
    #pragma unroll
    for (int k = 0; k < NSLOT; ++k) { v[k] = 0.0; ureg[k] = 0.0; pof[k] = 0; }
    // kc=3 covers idx 768..899 -> valid lanes 0..32 only
    const unsigned invalid = (lane <= 32) ? 0u : 0xF000u;
    double u_c0 = 0.0;

    // ---- exact SAP tree stage ----
    for (int ii = 0; ii < nfree; ++ii) {
        const int i = listA[ii];
        #pragma unroll
        for (int k = 0; k < NSLOT; ++k) minv[k] = INFINITY;
        unsigned used = invalid;
        int j0 = 0;
        int i0 = i;
        double u_i0 = u_s[i];
        int guard = 0;

        while (guard++ < MAXTREE) {
            // stage A: mark j0 used (owner lane records row + running u)
            if (j0 != 0) {
                int idx = j0 - 1;
                if (lane == ((idx >> 2) & 63)) {
                    int slot = ((idx >> 8) << 2) | (idx & 3);
                    used |= (1u << slot);
                    #pragma unroll
                    for (int s = 0; s < NSLOT; ++s)
                        if (s == slot) { pof[s] = i0; ureg[s] = u_i0; }
                }
            } else {
                if (lane == 0) u_c0 = u_i0;
            }

            // row fetch: 4x dwordx4, fully coalesced (L2-resident)
            const float4* crow4 = (const float4*)(cost + (size_t)(i0 - 1) * NQ);
            float4 c4[4];
            #pragma unroll
            for (int kc = 0; kc < 3; ++kc) c4[kc] = crow4[lane + 64 * kc];
            c4[3] = (lane <= 32) ? crow4[lane + 192] : make_float4(0.f, 0.f, 0.f, 0.f);

            // stage B: scan free columns (cur = (c - u) - v); lane-local argmin asc-j
            double bv = INFINITY;
            int bj = 2048;
            #pragma unroll
            for (int kc = 0; kc < 4; ++kc) {
                #pragma unroll
                for (int e = 0; e < 4; ++e) {
                    const int s = 4 * kc + e;
                    if (!((used >> s) & 1u)) {
                        float cf = (e == 0) ? c4[kc].x : (e == 1) ? c4[kc].y
                                 : (e == 2) ? c4[kc].z : c4[kc].w;
                        int j = 1 + 4 * lane + 256 * kc + e;
                        double cur = ((double)cf - u_i0) - v[s];
                        if (cur < minv[s]) { minv[s] = cur; way_s[j] = j0; }
                        if (minv[s] < bv) { bv = minv[s]; bj = j; }
                    }
                }
            }
            // value-only EXACT f64 min butterfly
            double vmin = bv;
            #pragma unroll
            for (int off = 1; off < 64; off <<= 1)
                vmin = fmin(vmin, __shfl_xor(vmin, off));
            // winner = first lane achieving the exact min; its bj (lane-local asc-j)
            unsigned long long tied = __ballot(bv == vmin);
            int wl = __ffsll((unsigned long long)tied) - 1;
            int jwin = __shfl(bj, wl);
            const double delta = vmin;

            // advance-read issued NOW so stage D's VALU work hides the LDS latency
            double2 t = pu[jwin];

            // stage D: dual update (register-resident)
            #pragma unroll
            for (int s = 0; s < NSLOT; ++s) {
                minv[s] -= delta;              // harmless for used slots (never read)
                if ((used >> s) & 1u) { ureg[s] += delta; v[s] -= delta; }
            }
            if (lane == 0) u_c0 += delta;

            j0 = jwin;
            i0 = (int)t.y;
            u_i0 = t.x;
            if (i0 == 0) break;
        }

        __syncthreads();
        // owner writebacks: u of rows sitting on used columns
        #pragma unroll
        for (int s = 0; s < NSLOT; ++s) {
            if (((used >> s) & 1u) && !((invalid >> s) & 1u)) {
                int j = 1 + 4 * lane + 256 * (s >> 2) + (s & 3);
                u_s[pof[s]] = ureg[s];
                pu[j] = make_double2(ureg[s], (double)pof[s]);
            }
        }
        __syncthreads();
        if (lane == 0) {
            u_s[i] = u_c0;
            int j = j0;
            while (j) {
                int jw = way_s[j];
                double2 t2 = (jw == 0) ? make_double2(u_c0, (double)i) : pu[jw];
                pu[j] = t2;
                j = jw;
            }
        }
        __syncthreads();
    }

    // ---- row2col + stable-argsort ranks ----
    for (int j = 1 + lane; j <= NQ; j += 64) {
        int pi = (int)pu[j].y;
        if (pi > 0) r2c[pi - 1] = j - 1;
    }
    __syncthreads();
    for (int t = lane; t < NT; t += 64) {
        int ccol = r2c[t];
        int rank = 0;
        for (int tt = 0; tt < NT; ++tt) rank += (r2c[tt] < ccol) ? 1 : 0;
        out[b * 2 * NT + rank] = ccol;         // out[b,0,rank] = pred idx
        out[b * 2 * NT + NT + rank] = t;       // out[b,1,rank] = target idx
    }
}

extern "C" void kernel_launch(void* const* d_in, const int* in_sizes, int n_in,
                              void* d_out, int out_size, void* d_ws, size_t ws_size,
                              hipStream_t stream) {
    const float* logits  = (const float*)d_in[0];  // (7,16,900,16)
    const float* pboxes  = (const float*)d_in[1];  // (16,900,4)
    const float* tboxes  = (const float*)d_in[2];  // (16,100,4)
    const int*   tlabels = (const int*)d_in[3];    // (7,16,100)
    int* out = (int*)d_out;                        // (16,2,100) int32
    float* costT = (float*)d_ws;                   // 1,440,000 floats = 5.76 MB

    const size_t costT_elems  = (size_t)BS * NT * NQ;
    const size_t probsT_elems = (size_t)NH * BS * NC * NQ;
    const size_t need = (costT_elems + probsT_elems) * sizeof(float);

    if (ws_size >= need) {
        float* probsT = costT + costT_elems;
        sig_transpose_kernel<<<NH * BS, 256, 0, stream>>>(logits, probsT);
        cost_kernel_bt<<<BS * NT, 256, 0, stream>>>((const float4*)pboxes,
                                                    (const float4*)tboxes, tlabels, probsT, costT);
    } else {
        const int total = BS * NT * NQ;
        cost_kernel_fb<<<(total + 255) / 256, 256, 0, stream>>>(logits, pboxes, tboxes, tlabels, costT);
    }
    lsa_kernel<<<BS, 64, 0, stream>>>(costT, out);
}